// Round 1
// baseline (13.371 us; speedup 1.0000x reference)
//
#include <hip/hip_runtime.h>
#include <stdint.h>

// SC polar decode, N=256, frozen = [0,128). Collapses to:
//   x_j = (in[b,j] + in[b,j+128] >= 0),  j in [0,128)
//   out[b,:] = T(x)  where T = F^{(x)7} over GF(2)  (self-inverse polar transform)
// One wave per batch row; 128 bits live in two 64-bit ballot masks; the
// butterfly is permutation-equivariant over index bits, so the ballot's
// bit packing (j = 2*(p mod 64) + (p>=64)) needs no de-interleave.
__global__ __launch_bounds__(256) void sc_dec_kernel(const float* __restrict__ in,
                                                     float* __restrict__ out,
                                                     int rows) {
    const int lane = threadIdx.x & 63;
    const int waves_per_block = blockDim.x >> 6;
    int wave = blockIdx.x * waves_per_block + (threadIdx.x >> 6);
    const int nwaves = gridDim.x * waves_per_block;

    for (int row = wave; row < rows; row += nwaves) {
        const float2* rin = reinterpret_cast<const float2*>(in + (size_t)row * 256);
        float2 a = rin[lane];        // in[2l], in[2l+1]
        float2 c = rin[64 + lane];   // in[128+2l], in[128+2l+1]

        // llr = -in; g = llr_l + llr_r; hard(g) = (g<=0) = (in_l+in_r >= 0)
        float s0 = a.x + c.x;
        float s1 = a.y + c.y;
        unsigned long long B0 = __ballot(s0 >= 0.0f);   // bit l <-> j = 2l
        unsigned long long B1 = __ballot(s1 >= 0.0f);   // bit l <-> j = 2l+1

        // 7-stage XOR butterfly u = T(x), run in the packed (p) bit-domain.
        unsigned long long w0 = B0 ^ B1;                // p-bit 6 stage
        unsigned long long w1 = B1;
        w0 ^= w0 >> 32;                                  w1 ^= w1 >> 32;
        w0 ^= (w0 >> 16) & 0x0000FFFF0000FFFFull;        w1 ^= (w1 >> 16) & 0x0000FFFF0000FFFFull;
        w0 ^= (w0 >> 8)  & 0x00FF00FF00FF00FFull;        w1 ^= (w1 >> 8)  & 0x00FF00FF00FF00FFull;
        w0 ^= (w0 >> 4)  & 0x0F0F0F0F0F0F0F0Full;        w1 ^= (w1 >> 4)  & 0x0F0F0F0F0F0F0F0Full;
        w0 ^= (w0 >> 2)  & 0x3333333333333333ull;        w1 ^= (w1 >> 2)  & 0x3333333333333333ull;
        w0 ^= (w0 >> 1)  & 0x5555555555555555ull;        w1 ^= (w1 >> 1)  & 0x5555555555555555ull;

        // u[2l] = bit l of w0, u[2l+1] = bit l of w1  (p(j) = 64*(j&1) + (j>>1))
        float2 o;
        o.x = (float)((w0 >> lane) & 1ull);
        o.y = (float)((w1 >> lane) & 1ull);
        reinterpret_cast<float2*>(out + (size_t)row * 128)[lane] = o;
    }
}

extern "C" void kernel_launch(void* const* d_in, const int* in_sizes, int n_in,
                              void* d_out, int out_size, void* d_ws, size_t ws_size,
                              hipStream_t stream) {
    const float* in = (const float*)d_in[0];
    float* out = (float*)d_out;
    const int rows = in_sizes[0] / 256;   // 32768

    const int threads = 256;              // 4 waves/block
    int blocks = 2048;                    // 8192 waves, grid-stride (4 rows/wave)
    int max_blocks = (rows + 3) / 4;      // never launch more waves than rows/1
    if (blocks > max_blocks) blocks = max_blocks;
    if (blocks < 1) blocks = 1;

    sc_dec_kernel<<<blocks, threads, 0, stream>>>(in, out, rows);
}

// Round 3
// 12.353 us; speedup vs baseline: 1.0824x; 1.0824x over previous
//
#include <hip/hip_runtime.h>
#include <stdint.h>

typedef unsigned long long u64;
typedef float f32x4 __attribute__((ext_vector_type(4)));   // native vec for nontemporal builtins

// SC polar decode, N=256, frozen = [0,128). Collapses to:
//   x_j = (in[b,j] + in[b,j+128] >= 0),  j in [0,128)
//   out[b,:] = T(x),  T = F^{(x)7} over GF(2) (self-inverse polar transform).
// T is equivariant under any permutation of the 7 index BITS, so we may run
// the word-butterfly in whatever packed bit-domain the ballots give us.

__device__ __forceinline__ void butterfly128(u64& w0, u64& w1) {
    w0 ^= w1;                                    // top index bit (word select)
    w0 ^= w0 >> 32;                              w1 ^= w1 >> 32;
    w0 ^= (w0 >> 16) & 0x0000FFFF0000FFFFull;    w1 ^= (w1 >> 16) & 0x0000FFFF0000FFFFull;
    w0 ^= (w0 >> 8)  & 0x00FF00FF00FF00FFull;    w1 ^= (w1 >> 8)  & 0x00FF00FF00FF00FFull;
    w0 ^= (w0 >> 4)  & 0x0F0F0F0F0F0F0F0Full;    w1 ^= (w1 >> 4)  & 0x0F0F0F0F0F0F0F0Full;
    w0 ^= (w0 >> 2)  & 0x3333333333333333ull;    w1 ^= (w1 >> 2)  & 0x3333333333333333ull;
    w0 ^= (w0 >> 1)  & 0x5555555555555555ull;    w1 ^= (w1 >> 1)  & 0x5555555555555555ull;
}

// Ballot masks for a row-PAIR: lanes 0-31 carry row pr (h=0), lanes 32-63 row
// pr+1 (h=1). Lane holds A = in[4m..4m+3], B = in[128+4m..128+4m+3] of row pr+h.
// Packed domain per row: P = 64*k1 + 32*k0 + m for j = 4m+k  (bit-permutation).
__device__ __forceinline__ void pair_masks(const f32x4& A, const f32x4& B,
                                           u64& wa0, u64& wa1, u64& wb0, u64& wb1) {
    u64 M0 = __ballot(A.x + B.x >= 0.0f);
    u64 M1 = __ballot(A.y + B.y >= 0.0f);
    u64 M2 = __ballot(A.z + B.z >= 0.0f);
    u64 M3 = __ballot(A.w + B.w >= 0.0f);
    wa0 = (M0 & 0xFFFFFFFFull) | (M1 << 32);          // row pr
    wa1 = (M2 & 0xFFFFFFFFull) | (M3 << 32);
    wb0 = (M0 >> 32) | (M1 & 0xFFFFFFFF00000000ull);  // row pr+1
    wb1 = (M2 >> 32) | (M3 & 0xFFFFFFFF00000000ull);
}

__global__ __launch_bounds__(256) void sc_dec_kernel(const float* __restrict__ in,
                                                     float* __restrict__ out,
                                                     int rows) {
    const int lane = threadIdx.x & 63;
    const int h = lane >> 5;          // which row of the pair this lane serves
    const int m = lane & 31;
    const int wave = blockIdx.x * (blockDim.x >> 6) + (threadIdx.x >> 6);
    const int r = wave * 4;           // 4 rows per wave (2 pairs)
    if (r >= rows) return;

    if (r + 4 <= rows) {
        const f32x4* b0 = reinterpret_cast<const f32x4*>(in + (size_t)r * 256);
        const f32x4* b1 = reinterpret_cast<const f32x4*>(in + (size_t)(r + 2) * 256);
        const int oA = (h << 6) + m;  // row (pr+h) first half  (float4 units)
        const int oB = oA + 32;       // row (pr+h) second half
        // hoist all 4 loads (4 KiB in flight per wave)
        f32x4 A0 = __builtin_nontemporal_load(&b0[oA]);
        f32x4 B0 = __builtin_nontemporal_load(&b0[oB]);
        f32x4 A1 = __builtin_nontemporal_load(&b1[oA]);
        f32x4 B1 = __builtin_nontemporal_load(&b1[oB]);

        u64 a0, a1, c0, c1;
        pair_masks(A0, B0, a0, a1, c0, c1);
        butterfly128(a0, a1);
        butterfly128(c0, c1);
        u64 w0 = h ? c0 : a0, w1 = h ? c1 : a1;
        f32x4 o;
        o.x = (float)((w0 >> m) & 1ull);
        o.y = (float)((w0 >> (m + 32)) & 1ull);
        o.z = (float)((w1 >> m) & 1ull);
        o.w = (float)((w1 >> (m + 32)) & 1ull);
        f32x4* ob0 = reinterpret_cast<f32x4*>(out + (size_t)r * 128);
        __builtin_nontemporal_store(o, &ob0[(h << 5) + m]);

        pair_masks(A1, B1, a0, a1, c0, c1);
        butterfly128(a0, a1);
        butterfly128(c0, c1);
        w0 = h ? c0 : a0; w1 = h ? c1 : a1;
        o.x = (float)((w0 >> m) & 1ull);
        o.y = (float)((w0 >> (m + 32)) & 1ull);
        o.z = (float)((w1 >> m) & 1ull);
        o.w = (float)((w1 >> (m + 32)) & 1ull);
        f32x4* ob1 = reinterpret_cast<f32x4*>(out + (size_t)(r + 2) * 128);
        __builtin_nontemporal_store(o, &ob1[(h << 5) + m]);
    } else {
        // tail fallback (rows % 4 != 0): round-0 per-row float2 scheme
        for (int row = r; row < rows; ++row) {
            const float2* rin = reinterpret_cast<const float2*>(in + (size_t)row * 256);
            float2 a = rin[lane];
            float2 c = rin[64 + lane];
            u64 B0 = __ballot(a.x + c.x >= 0.0f);
            u64 B1 = __ballot(a.y + c.y >= 0.0f);
            u64 w0 = B0;
            u64 w1 = B1;
            w0 ^= w1;  // top stage in packed domain
            w0 ^= w0 >> 32;                              w1 ^= w1 >> 32;
            w0 ^= (w0 >> 16) & 0x0000FFFF0000FFFFull;    w1 ^= (w1 >> 16) & 0x0000FFFF0000FFFFull;
            w0 ^= (w0 >> 8)  & 0x00FF00FF00FF00FFull;    w1 ^= (w1 >> 8)  & 0x00FF00FF00FF00FFull;
            w0 ^= (w0 >> 4)  & 0x0F0F0F0F0F0F0F0Full;    w1 ^= (w1 >> 4)  & 0x0F0F0F0F0F0F0F0Full;
            w0 ^= (w0 >> 2)  & 0x3333333333333333ull;    w1 ^= (w1 >> 2)  & 0x3333333333333333ull;
            w0 ^= (w0 >> 1)  & 0x5555555555555555ull;    w1 ^= (w1 >> 1)  & 0x5555555555555555ull;
            float2 o;
            o.x = (float)((w0 >> lane) & 1ull);
            o.y = (float)((w1 >> lane) & 1ull);
            reinterpret_cast<float2*>(out + (size_t)row * 128)[lane] = o;
        }
    }
}

extern "C" void kernel_launch(void* const* d_in, const int* in_sizes, int n_in,
                              void* d_out, int out_size, void* d_ws, size_t ws_size,
                              hipStream_t stream) {
    const float* in = (const float*)d_in[0];
    float* out = (float*)d_out;
    const int rows = in_sizes[0] / 256;            // 32768

    const int waves = (rows + 3) / 4;              // 4 rows per wave
    const int blocks = (waves + 3) / 4;            // 4 waves per 256-thread block
    sc_dec_kernel<<<blocks, 256, 0, stream>>>(in, out, rows);
}